// Round 8
// baseline (46.570 us; speedup 1.0000x reference)
//
#include <hip/hip_runtime.h>
#include <hip/hip_bf16.h>
#include <math.h>

constexpr int T = 128;
constexpr int B = 128;
constexpr int R = 512;
constexpr int NS = 256;   // 2*T slots

typedef __attribute__((ext_vector_type(8))) short bf16x8;
typedef __attribute__((ext_vector_type(4))) float f32x4;

static __device__ __forceinline__ ushort f2bf(float f) {
    union { float f; unsigned u; } v; v.f = f;
    unsigned r = v.u + 0x7fffu + ((v.u >> 16) & 1u);   // RNE
    return (ushort)(r >> 16);
}

// ---------------------------------------------------------------------------
// Kernel 0: hscan — H_t = max(0, H_{t-1} + d1+d2-u) via parallel scan:
//   H_t = P_t - min(0, min_{k<=t} P_k),  P = prefix sum of e.
// Wave = one batch; lane = t (two 64-halves with carry). Grid 64 x 128thr.
// ---------------------------------------------------------------------------
__global__ __launch_bounds__(128) void hscan(
    const float* __restrict__ u, const float* __restrict__ d1,
    const float* __restrict__ d2, float* __restrict__ H)
{
    const int b    = blockIdx.x * 2 + (threadIdx.x >> 6);
    const int lane = threadIdx.x & 63;

    // half 1: t = lane
    int idx = lane * B + b;
    float P = d1[idx] + d2[idx] - u[idx];
    #pragma unroll
    for (int off = 1; off < 64; off <<= 1) {
        float o = __shfl_up(P, off);
        if (lane >= off) P += o;
    }
    float M = P;
    #pragma unroll
    for (int off = 1; off < 64; off <<= 1) {
        float o = __shfl_up(M, off);
        if (lane >= off) M = fminf(M, o);
    }
    H[idx] = P - fminf(0.f, M);
    const float carryP = __shfl(P, 63);
    const float carryM = fminf(0.f, __shfl(M, 63));   // <= 0

    // half 2: t = 64 + lane
    idx = (64 + lane) * B + b;
    float p2 = d1[idx] + d2[idx] - u[idx];
    #pragma unroll
    for (int off = 1; off < 64; off <<= 1) {
        float o = __shfl_up(p2, off);
        if (lane >= off) p2 += o;
    }
    float m2 = p2;
    #pragma unroll
    for (int off = 1; off < 64; off <<= 1) {
        float o = __shfl_up(m2, off);
        if (lane >= off) m2 = fminf(m2, o);
    }
    const float Pt = carryP + p2;
    H[idx] = Pt - fminf(carryM, carryP + m2);
}

// ---------------------------------------------------------------------------
// Kernel 1: closed-form weights, bf16 out. Block = one t, 512 thr (8 waves).
// H read from global (L2-hot, coalesced). LDS = 4 KB smin only.
// Phase A2: wave wv -> per-batch min of H over stripe [16wv,16wv+16)∩[0,t).
// Phase B : wave wv owns p in [16wv, min(16wv+15,t)]; m seeded from smin;
//           val/base register carry + distance-2 H prefetch; 64-lane
//           shfl_xor max for scal. Lane owns batches (lane, lane+64).
// Phase C : zero-fill never-pushed slot groups.
// ---------------------------------------------------------------------------
__global__ __launch_bounds__(512) void weights(
    const float* __restrict__ u, const float* __restrict__ d1,
    const float* __restrict__ d2, const float* __restrict__ H,
    ushort* __restrict__ w)
{
    const int t    = blockIdx.x;
    const int tid  = threadIdx.x;
    const int wv   = tid >> 6;          // 0..7
    const int lane = tid & 63;
    __shared__ float smin[8][B];        // 4 KB

    const int b0 = lane, b1 = lane + 64;

    // Phase A2: stripe minima
    {
        const int rs = wv * 16;
        const int re = min(rs + 16, t);     // exclusive
        float sa = 1e30f, sb = 1e30f;
        #pragma unroll 4
        for (int tau = rs; tau < re; ++tau) {
            sa = fminf(sa, H[tau * B + b0]);
            sb = fminf(sb, H[tau * B + b1]);
        }
        smin[wv][b0] = sa;
        smin[wv][b1] = sb;
    }
    __syncthreads();

    const float Ht1a = (t > 0) ? H[(t-1)*B + b0] : 0.f;
    const float Ht1b = (t > 0) ? H[(t-1)*B + b1] : 0.f;
    const float Hpa  = Ht1a + d1[t*B+b0] + d2[t*B+b0];   // H'_t
    const float Hpb  = Ht1b + d1[t*B+b1] + d2[t*B+b1];
    const float Aa   = u[t*B+b0] - Hpa;
    const float Ab   = u[t*B+b1] - Hpb;

    ushort* wrow0 = w + ((size_t)t * B + b0) * NS;
    ushort* wrow1 = w + ((size_t)t * B + b1) * NS;

    const int plo = wv * 16;
    if (plo <= t) {
        const int pe = min(plo + 15, t);
        float ma = 1e30f, mb = 1e30f;       // seed: min over stripes > wv
        #pragma unroll
        for (int s = 0; s < 8; ++s) {
            if (s > wv) { ma = fminf(ma, smin[s][b0]); mb = fminf(mb, smin[s][b1]); }
        }
        // register carry: val = H[p], base = H[p-1], pnb = base for next iter
        float vala = (pe < t) ? H[pe*B + b0] : 0.f;
        float valb = (pe < t) ? H[pe*B + b1] : 0.f;
        float basea = (pe > 0) ? H[(pe-1)*B + b0] : 0.f;
        float baseb = (pe > 0) ? H[(pe-1)*B + b1] : 0.f;
        float pnb_a = (pe > 1) ? H[(pe-2)*B + b0] : 0.f;
        float pnb_b = (pe > 1) ? H[(pe-2)*B + b1] : 0.f;
        float nd1a = d1[pe*B+b0], nd1b = d1[pe*B+b1];
        float nd2a = d2[pe*B+b0], nd2b = d2[pe*B+b1];
        float s2a = 0.f, s3a = 0.f, s2b = 0.f, s3b = 0.f;

        for (int p = pe; p >= plo; --p) {
            const float d1a = nd1a, d1b = nd1b, d2a = nd2a, d2b = nd2b;
            if (p > plo) {
                nd1a = d1[(p-1)*B+b0]; nd1b = d1[(p-1)*B+b1];
                nd2a = d2[(p-1)*B+b0]; nd2b = d2[(p-1)*B+b1];
            }
            if (p < t) { ma = fminf(ma, vala); mb = fminf(mb, valb); }
            const float top0a = basea + d1a, top0b = baseb + d1b;
            const float top1a = top0a + d2a, top1b = top0b + d2b;

            const float sa0 = fminf(fmaxf(ma - basea, 0.f), d1a);
            const float sb0 = fminf(fmaxf(mb - baseb, 0.f), d1b);
            const float sa1 = fminf(fmaxf(ma - top0a, 0.f), d2a);
            const float sb1 = fminf(fmaxf(mb - top0b, 0.f), d2b);

            float cand0 = fmaxf(Aa + fminf(top0a, ma), Ab + fminf(top0b, mb));
            float cand1 = fmaxf(Aa + fminf(top1a, ma), Ab + fminf(top1b, mb));
            #pragma unroll
            for (int off = 32; off >= 1; off >>= 1) {
                cand0 = fmaxf(cand0, __shfl_xor(cand0, off));
                cand1 = fmaxf(cand1, __shfl_xor(cand1, off));
            }

            const float w0a = fminf(sa0, cand0), w0b = fminf(sb0, cand0);
            const float w1a = fminf(sa1, cand1), w1b = fminf(sb1, cand1);
            if (p & 1) { s2a = w0a; s3a = w1a; s2b = w0b; s3b = w1b; }
            else {
                const int g = p >> 1;
                *(ushort4*)(wrow0 + 4*g) =
                    make_ushort4(f2bf(w0a), f2bf(w1a), f2bf(s2a), f2bf(s3a));
                *(ushort4*)(wrow1 + 4*g) =
                    make_ushort4(f2bf(w0b), f2bf(w1b), f2bf(s2b), f2bf(s3b));
            }
            // rotate carries; prefetch base for iteration p-2
            vala = basea; valb = baseb;
            basea = pnb_a; baseb = pnb_b;
            if (p - 2 >= plo) {
                pnb_a = (p >= 3) ? H[(p-3)*B + b0] : 0.f;
                pnb_b = (p >= 3) ? H[(p-3)*B + b1] : 0.f;
            }
        }
    }

    // Phase C
    const int gstart = (t >> 1) + 1;
    const int ng = (NS / 4) - gstart;
    if (ng > 0) {
        const ushort4 z = make_ushort4(0, 0, 0, 0);
        const int total = ng * B;
        for (int idx = tid; idx < total; idx += 512) {
            const int gi = idx % ng;
            const int bb = idx / ng;
            *(ushort4*)(w + ((size_t)t*B + bb)*NS + 4*(gstart + gi)) = z;
        }
    }
}

// ---------------------------------------------------------------------------
// Kernel 2: bf16 MFMA GEMM — R6 staging structure, RT=64.
// Grid (b, 8 r-tiles) = 1024 blocks = 4/CU; 512 thr = 8 waves.
// Wave wv owns t in [16wv,16wv+16) x 64 r (4 16x16x32 frags).
// V-stage: every thread loads ONE float4 (tid<256 -> v1, else v2), writes 4
// b16 LDS halves (interleaved j). A-stage unconditional (w tail is zeroed).
// Zero-structure: wave wv skips MFMA for chunk c > wv.
// ---------------------------------------------------------------------------
#define RT 64
__global__ __launch_bounds__(512) void gemm_mfma(
    const ushort* __restrict__ w, const float* __restrict__ v1,
    const float* __restrict__ v2, float* __restrict__ out)
{
    const int b    = blockIdx.x;
    const int r0   = blockIdx.y * RT;
    const int tid  = threadIdx.x;
    const int wv   = tid >> 6;          // 0..7
    const int lane = tid & 63;

    __shared__ ushort As[2][128][40];   // [t][j] bf16, 20 KB
    __shared__ ushort Bs[2][RT][40];    // [r][j] bf16, 10 KB

    // A staging: 4 threads per t-row, each 8 j (16 B)
    const int arow = tid >> 2;          // 0..127
    const int ajh  = (tid & 3) * 8;     // 0,8,16,24
    const ushort* abase = w + ((size_t)arow * B + b) * NS + ajh;

    // B staging: thread = (p2 0..15, rseg 0..15, jodd)
    const int p2   = tid & 15;
    const int rseg = (tid >> 4) & 15;
    const int jodd = tid >> 8;          // 0: v1 (even j), 1: v2 (odd j)
    const float* vb = (jodd ? v2 : v1) + (size_t)b * R + r0 + rseg * 4;

    f32x4 acc[4];
    const f32x4 zz = {0.f, 0.f, 0.f, 0.f};
    #pragma unroll
    for (int i = 0; i < 4; ++i) acc[i] = zz;

    uint4 la;
    float4 lv;

    #define STAGE_LOAD(c) do {                                          \
        la = *(const uint4*)(abase + (c) * 32);                         \
        lv = *(const float4*)(vb + (size_t)((c) * 16 + p2) * B * R);    \
    } while (0)

    #define STAGE_WRITE(buf) do {                                       \
        *(uint4*)&As[buf][arow][ajh] = la;                              \
        const float* f_ = (const float*)&lv;                            \
        _Pragma("unroll")                                               \
        for (int i_ = 0; i_ < 4; ++i_)                                  \
            Bs[buf][rseg * 4 + i_][p2 * 2 + jodd] = f2bf(f_[i_]);       \
    } while (0)

    const int tb = wv * 16 + (lane & 15);
    const int ko = (lane >> 4) * 8;

    STAGE_LOAD(0);
    STAGE_WRITE(0);
    #pragma unroll
    for (int c = 0; c < 8; ++c) {
        const int buf = c & 1;
        if (c < 7) STAGE_LOAD(c + 1);
        __syncthreads();
        if (c <= wv) {                  // chunks beyond this are all-zero A
            bf16x8 a0 = *(const bf16x8*)&As[buf][tb][ko];
            #pragma unroll
            for (int cf = 0; cf < 4; ++cf) {
                bf16x8 bb = *(const bf16x8*)&Bs[buf][cf*16 + (lane & 15)][ko];
                acc[cf] = __builtin_amdgcn_mfma_f32_16x16x32_bf16(a0, bb, acc[cf], 0, 0, 0);
            }
        }
        if (c < 7) STAGE_WRITE((c + 1) & 1);
    }

    // epilogue: D col = lane&15 (r), row = (lane>>4)*4 + i (t)
    const int dcol  = lane & 15;
    const int drow4 = (lane >> 4) * 4;
    #pragma unroll
    for (int cf = 0; cf < 4; ++cf) {
        const int rg = r0 + cf * 16 + dcol;
        #pragma unroll
        for (int i = 0; i < 4; ++i) {
            const int tg = wv * 16 + drow4 + i;
            out[((size_t)tg * B + b) * R + rg] = acc[cf][i];
        }
    }
    #undef STAGE_LOAD
    #undef STAGE_WRITE
}

extern "C" void kernel_launch(void* const* d_in, const int* in_sizes, int n_in,
                              void* d_out, int out_size, void* d_ws, size_t ws_size,
                              hipStream_t stream) {
    const float* u  = (const float*)d_in[0];
    const float* d1 = (const float*)d_in[1];
    const float* d2 = (const float*)d_in[2];
    const float* v1 = (const float*)d_in[3];
    const float* v2 = (const float*)d_in[4];
    float* out = (float*)d_out;

    const size_t welems = (size_t)T * B * NS;         // 4.19M ushorts
    ushort* w = (ushort*)d_ws;                        // 8.39 MB
    float* H;
    if (ws_size >= welems * sizeof(ushort) + (size_t)T * B * sizeof(float)) {
        H = (float*)((char*)d_ws + welems * sizeof(ushort));
    } else {
        // 64 KB parked at start of d_out; dead before gemm overwrites it
        H = (float*)d_out;
    }

    hscan  <<<dim3(B / 2), dim3(128), 0, stream>>>(u, d1, d2, H);
    weights<<<dim3(T),     dim3(512), 0, stream>>>(u, d1, d2, H, w);
    gemm_mfma<<<dim3(B, R / RT), dim3(512), 0, stream>>>(w, v1, v2, out);
}

// Round 9
// 43.263 us; speedup vs baseline: 1.0764x; 1.0764x over previous
//
#include <hip/hip_runtime.h>
#include <hip/hip_bf16.h>
#include <math.h>

constexpr int T = 128;
constexpr int B = 128;
constexpr int R = 512;
constexpr int NS = 256;   // 2*T slots

typedef __attribute__((ext_vector_type(8))) short bf16x8;
typedef __attribute__((ext_vector_type(4))) float f32x4;

static __device__ __forceinline__ ushort f2bf(float f) {
    union { float f; unsigned u; } v; v.f = f;
    unsigned r = v.u + 0x7fffu + ((v.u >> 16) & 1u);   // RNE
    return (ushort)(r >> 16);
}

// ---------------------------------------------------------------------------
// Kernel 0: hscan — H_t = max(0, H_{t-1} + d1+d2-u) via parallel scan:
//   H_t = P_t - min(0, min_{k<=t} P_k),  P = prefix sum of e.
// Wave = one batch; lane = t (two 64-halves with carry). Grid 64 x 128thr.
// ---------------------------------------------------------------------------
__global__ __launch_bounds__(128) void hscan(
    const float* __restrict__ u, const float* __restrict__ d1,
    const float* __restrict__ d2, float* __restrict__ H)
{
    const int b    = blockIdx.x * 2 + (threadIdx.x >> 6);
    const int lane = threadIdx.x & 63;

    int idx = lane * B + b;
    float P = d1[idx] + d2[idx] - u[idx];
    #pragma unroll
    for (int off = 1; off < 64; off <<= 1) {
        float o = __shfl_up(P, off);
        if (lane >= off) P += o;
    }
    float M = P;
    #pragma unroll
    for (int off = 1; off < 64; off <<= 1) {
        float o = __shfl_up(M, off);
        if (lane >= off) M = fminf(M, o);
    }
    H[idx] = P - fminf(0.f, M);
    const float carryP = __shfl(P, 63);
    const float carryM = fminf(0.f, __shfl(M, 63));   // <= 0

    idx = (64 + lane) * B + b;
    float p2 = d1[idx] + d2[idx] - u[idx];
    #pragma unroll
    for (int off = 1; off < 64; off <<= 1) {
        float o = __shfl_up(p2, off);
        if (lane >= off) p2 += o;
    }
    float m2 = p2;
    #pragma unroll
    for (int off = 1; off < 64; off <<= 1) {
        float o = __shfl_up(m2, off);
        if (lane >= off) m2 = fminf(m2, o);
    }
    const float Pt = carryP + p2;
    H[idx] = Pt - fminf(carryM, carryP + m2);
}

// ---------------------------------------------------------------------------
// Kernel 1: closed-form weights, bf16 out. Block = one t, 512 thr (8 waves).
// (R8 version — H from global, 4 KB LDS smin only)
// ---------------------------------------------------------------------------
__global__ __launch_bounds__(512) void weights(
    const float* __restrict__ u, const float* __restrict__ d1,
    const float* __restrict__ d2, const float* __restrict__ H,
    ushort* __restrict__ w)
{
    const int t    = blockIdx.x;
    const int tid  = threadIdx.x;
    const int wv   = tid >> 6;          // 0..7
    const int lane = tid & 63;
    __shared__ float smin[8][B];        // 4 KB

    const int b0 = lane, b1 = lane + 64;

    // Phase A2: stripe minima
    {
        const int rs = wv * 16;
        const int re = min(rs + 16, t);     // exclusive
        float sa = 1e30f, sb = 1e30f;
        #pragma unroll 4
        for (int tau = rs; tau < re; ++tau) {
            sa = fminf(sa, H[tau * B + b0]);
            sb = fminf(sb, H[tau * B + b1]);
        }
        smin[wv][b0] = sa;
        smin[wv][b1] = sb;
    }
    __syncthreads();

    const float Ht1a = (t > 0) ? H[(t-1)*B + b0] : 0.f;
    const float Ht1b = (t > 0) ? H[(t-1)*B + b1] : 0.f;
    const float Hpa  = Ht1a + d1[t*B+b0] + d2[t*B+b0];   // H'_t
    const float Hpb  = Ht1b + d1[t*B+b1] + d2[t*B+b1];
    const float Aa   = u[t*B+b0] - Hpa;
    const float Ab   = u[t*B+b1] - Hpb;

    ushort* wrow0 = w + ((size_t)t * B + b0) * NS;
    ushort* wrow1 = w + ((size_t)t * B + b1) * NS;

    const int plo = wv * 16;
    if (plo <= t) {
        const int pe = min(plo + 15, t);
        float ma = 1e30f, mb = 1e30f;       // seed: min over stripes > wv
        #pragma unroll
        for (int s = 0; s < 8; ++s) {
            if (s > wv) { ma = fminf(ma, smin[s][b0]); mb = fminf(mb, smin[s][b1]); }
        }
        float vala = (pe < t) ? H[pe*B + b0] : 0.f;
        float valb = (pe < t) ? H[pe*B + b1] : 0.f;
        float basea = (pe > 0) ? H[(pe-1)*B + b0] : 0.f;
        float baseb = (pe > 0) ? H[(pe-1)*B + b1] : 0.f;
        float pnb_a = (pe > 1) ? H[(pe-2)*B + b0] : 0.f;
        float pnb_b = (pe > 1) ? H[(pe-2)*B + b1] : 0.f;
        float nd1a = d1[pe*B+b0], nd1b = d1[pe*B+b1];
        float nd2a = d2[pe*B+b0], nd2b = d2[pe*B+b1];
        float s2a = 0.f, s3a = 0.f, s2b = 0.f, s3b = 0.f;

        for (int p = pe; p >= plo; --p) {
            const float d1a = nd1a, d1b = nd1b, d2a = nd2a, d2b = nd2b;
            if (p > plo) {
                nd1a = d1[(p-1)*B+b0]; nd1b = d1[(p-1)*B+b1];
                nd2a = d2[(p-1)*B+b0]; nd2b = d2[(p-1)*B+b1];
            }
            if (p < t) { ma = fminf(ma, vala); mb = fminf(mb, valb); }
            const float top0a = basea + d1a, top0b = baseb + d1b;
            const float top1a = top0a + d2a, top1b = top0b + d2b;

            const float sa0 = fminf(fmaxf(ma - basea, 0.f), d1a);
            const float sb0 = fminf(fmaxf(mb - baseb, 0.f), d1b);
            const float sa1 = fminf(fmaxf(ma - top0a, 0.f), d2a);
            const float sb1 = fminf(fmaxf(mb - top0b, 0.f), d2b);

            float cand0 = fmaxf(Aa + fminf(top0a, ma), Ab + fminf(top0b, mb));
            float cand1 = fmaxf(Aa + fminf(top1a, ma), Ab + fminf(top1b, mb));
            #pragma unroll
            for (int off = 32; off >= 1; off >>= 1) {
                cand0 = fmaxf(cand0, __shfl_xor(cand0, off));
                cand1 = fmaxf(cand1, __shfl_xor(cand1, off));
            }

            const float w0a = fminf(sa0, cand0), w0b = fminf(sb0, cand0);
            const float w1a = fminf(sa1, cand1), w1b = fminf(sb1, cand1);
            if (p & 1) { s2a = w0a; s3a = w1a; s2b = w0b; s3b = w1b; }
            else {
                const int g = p >> 1;
                *(ushort4*)(wrow0 + 4*g) =
                    make_ushort4(f2bf(w0a), f2bf(w1a), f2bf(s2a), f2bf(s3a));
                *(ushort4*)(wrow1 + 4*g) =
                    make_ushort4(f2bf(w0b), f2bf(w1b), f2bf(s2b), f2bf(s3b));
            }
            vala = basea; valb = baseb;
            basea = pnb_a; baseb = pnb_b;
            if (p - 2 >= plo) {
                pnb_a = (p >= 3) ? H[(p-3)*B + b0] : 0.f;
                pnb_b = (p >= 3) ? H[(p-3)*B + b1] : 0.f;
            }
        }
    }

    // Phase C
    const int gstart = (t >> 1) + 1;
    const int ng = (NS / 4) - gstart;
    if (ng > 0) {
        const ushort4 z = make_ushort4(0, 0, 0, 0);
        const int total = ng * B;
        for (int idx = tid; idx < total; idx += 512) {
            const int gi = idx % ng;
            const int bb = idx / ng;
            *(ushort4*)(w + ((size_t)t*B + bb)*NS + 4*(gstart + gi)) = z;
        }
    }
}

// ---------------------------------------------------------------------------
// Kernel 2: bf16 MFMA GEMM — exact R6/R7 structure (best measured family).
// Block = (b, r-tile 128), grid 512; 512 thr = 8 waves; wave wv owns
// t in [16wv,16wv+16) x 128 r. Zero-skip: MFMA only for chunk c <= wv;
// A-stage rows arow < 16c write zeros instead of loading.
// ---------------------------------------------------------------------------
#define RT 128
__global__ __launch_bounds__(512) void gemm_mfma(
    const ushort* __restrict__ w, const float* __restrict__ v1,
    const float* __restrict__ v2, float* __restrict__ out)
{
    const int b    = blockIdx.x;
    const int r0   = blockIdx.y * RT;
    const int tid  = threadIdx.x;
    const int wv   = tid >> 6;          // 0..7
    const int lane = tid & 63;

    __shared__ ushort As[2][128][40];   // [t][j] bf16, pitch 40
    __shared__ ushort Bs[2][128][40];   // [r][j] bf16 (V transposed)

    const int arow = tid >> 2;          // 0..127
    const int ajh  = (tid & 3) * 8;     // 0,8,16,24
    const ushort* abase = w + ((size_t)arow * B + b) * NS + ajh;

    const int p2   = tid & 15;
    const int rseg = tid >> 4;          // 0..31
    const float* v1b = v1 + (size_t)b * R + r0 + rseg * 4;
    const float* v2b = v2 + (size_t)b * R + r0 + rseg * 4;

    f32x4 acc[8];
    const f32x4 zz = {0.f, 0.f, 0.f, 0.f};
    #pragma unroll
    for (int i = 0; i < 8; ++i) acc[i] = zz;

    uint4 la;
    float4 lv1, lv2;

    #define STAGE_LOAD(c) do {                                          \
        if (arow >= 16 * (c)) {                                         \
            la = *(const uint4*)(abase + (c) * 32);                     \
        } else {                                                        \
            la = make_uint4(0u, 0u, 0u, 0u);                            \
        }                                                               \
        const size_t off_ = (size_t)((c) * 16 + p2) * B * R;            \
        lv1 = *(const float4*)(v1b + off_);                             \
        lv2 = *(const float4*)(v2b + off_);                             \
    } while (0)

    #define STAGE_WRITE(buf) do {                                       \
        *(uint4*)&As[buf][arow][ajh] = la;                              \
        const float* f1_ = (const float*)&lv1;                          \
        const float* f2_ = (const float*)&lv2;                          \
        _Pragma("unroll")                                               \
        for (int i_ = 0; i_ < 4; ++i_) {                                \
            unsigned pk_ = (unsigned)f2bf(f1_[i_]) |                    \
                           ((unsigned)f2bf(f2_[i_]) << 16);             \
            *(unsigned*)&Bs[buf][rseg * 4 + i_][p2 * 2] = pk_;          \
        }                                                               \
    } while (0)

    const int tb = wv * 16 + (lane & 15);
    const int ko = (lane >> 4) * 8;

    STAGE_LOAD(0);
    STAGE_WRITE(0);
    #pragma unroll
    for (int c = 0; c < 8; ++c) {
        const int buf = c & 1;
        if (c < 7) STAGE_LOAD(c + 1);
        __syncthreads();
        if (c <= wv) {                  // chunks beyond this are all-zero A
            bf16x8 a0 = *(const bf16x8*)&As[buf][tb][ko];
            #pragma unroll
            for (int cf = 0; cf < 8; ++cf) {
                bf16x8 bb = *(const bf16x8*)&Bs[buf][cf*16 + (lane & 15)][ko];
                acc[cf] = __builtin_amdgcn_mfma_f32_16x16x32_bf16(a0, bb, acc[cf], 0, 0, 0);
            }
        }
        if (c < 7) STAGE_WRITE((c + 1) & 1);
    }

    const int dcol  = lane & 15;
    const int drow4 = (lane >> 4) * 4;
    #pragma unroll
    for (int cf = 0; cf < 8; ++cf) {
        const int rg = r0 + cf * 16 + dcol;
        #pragma unroll
        for (int i = 0; i < 4; ++i) {
            const int tg = wv * 16 + drow4 + i;
            out[((size_t)tg * B + b) * R + rg] = acc[cf][i];
        }
    }
    #undef STAGE_LOAD
    #undef STAGE_WRITE
}

extern "C" void kernel_launch(void* const* d_in, const int* in_sizes, int n_in,
                              void* d_out, int out_size, void* d_ws, size_t ws_size,
                              hipStream_t stream) {
    const float* u  = (const float*)d_in[0];
    const float* d1 = (const float*)d_in[1];
    const float* d2 = (const float*)d_in[2];
    const float* v1 = (const float*)d_in[3];
    const float* v2 = (const float*)d_in[4];
    float* out = (float*)d_out;

    const size_t welems = (size_t)T * B * NS;         // 4.19M ushorts
    ushort* w = (ushort*)d_ws;                        // 8.39 MB
    float* H;
    if (ws_size >= welems * sizeof(ushort) + (size_t)T * B * sizeof(float)) {
        H = (float*)((char*)d_ws + welems * sizeof(ushort));
    } else {
        H = (float*)d_out;   // 64 KB, dead before gemm overwrites it
    }

    hscan  <<<dim3(B / 2), dim3(128), 0, stream>>>(u, d1, d2, H);
    weights<<<dim3(T),     dim3(512), 0, stream>>>(u, d1, d2, H, w);
    gemm_mfma<<<dim3(B, R / RT), dim3(512), 0, stream>>>(w, v1, v2, out);
}

// Round 10
// 42.398 us; speedup vs baseline: 1.0984x; 1.0204x over previous
//
#include <hip/hip_runtime.h>
#include <hip/hip_bf16.h>
#include <math.h>

constexpr int T = 128;
constexpr int B = 128;
constexpr int R = 512;
constexpr int NS = 256;   // 2*T slots

typedef __attribute__((ext_vector_type(8))) short bf16x8;
typedef __attribute__((ext_vector_type(4))) float f32x4;

static __device__ __forceinline__ ushort f2bf(float f) {
    union { float f; unsigned u; } v; v.f = f;
    unsigned r = v.u + 0x7fffu + ((v.u >> 16) & 1u);   // RNE
    return (ushort)(r >> 16);
}

// ---------------------------------------------------------------------------
// Kernel 0: hscan — H_t = max(0, H_{t-1} + d1+d2-u) via parallel scan:
//   H_t = P_t - min(0, min_{k<=t} P_k),  P = prefix sum of e.
// Wave = one batch; lane = t (two 64-halves with carry). Grid 64 x 128thr.
// ---------------------------------------------------------------------------
__global__ __launch_bounds__(128) void hscan(
    const float* __restrict__ u, const float* __restrict__ d1,
    const float* __restrict__ d2, float* __restrict__ H)
{
    const int b    = blockIdx.x * 2 + (threadIdx.x >> 6);
    const int lane = threadIdx.x & 63;

    int idx = lane * B + b;
    float P = d1[idx] + d2[idx] - u[idx];
    #pragma unroll
    for (int off = 1; off < 64; off <<= 1) {
        float o = __shfl_up(P, off);
        if (lane >= off) P += o;
    }
    float M = P;
    #pragma unroll
    for (int off = 1; off < 64; off <<= 1) {
        float o = __shfl_up(M, off);
        if (lane >= off) M = fminf(M, o);
    }
    H[idx] = P - fminf(0.f, M);
    const float carryP = __shfl(P, 63);
    const float carryM = fminf(0.f, __shfl(M, 63));   // <= 0

    idx = (64 + lane) * B + b;
    float p2 = d1[idx] + d2[idx] - u[idx];
    #pragma unroll
    for (int off = 1; off < 64; off <<= 1) {
        float o = __shfl_up(p2, off);
        if (lane >= off) p2 += o;
    }
    float m2 = p2;
    #pragma unroll
    for (int off = 1; off < 64; off <<= 1) {
        float o = __shfl_up(m2, off);
        if (lane >= off) m2 = fminf(m2, o);
    }
    const float Pt = carryP + p2;
    H[idx] = Pt - fminf(carryM, carryP + m2);
}

// ---------------------------------------------------------------------------
// Kernel 1: closed-form weights, bf16 out. Block = one t, 512 thr (8 waves).
// Phase A0: stage H rows [0,t) from global into LDS (coalesced float4) —
//           replaces R7's serial in-block H recurrence (hscan provides H).
// Phase A2: wave wv -> per-batch min of H over stripe [16wv,16wv+16)∩[0,t).
// Phase B : R7's proven LDS p-loop — wave wv owns p in [16wv,min(16wv+15,t)];
//           m seeded from smin; 64-lane shfl_xor max for scal.
// Phase C : zero-fill never-pushed slot groups.
// ---------------------------------------------------------------------------
__global__ __launch_bounds__(512) void weights(
    const float* __restrict__ u, const float* __restrict__ d1,
    const float* __restrict__ d2, const float* __restrict__ H,
    ushort* __restrict__ w)
{
    const int t    = blockIdx.x;
    const int tid  = threadIdx.x;
    const int wv   = tid >> 6;          // 0..7
    const int lane = tid & 63;
    __shared__ float eH[T][B];          // 64 KB (holds H rows [0,t))
    __shared__ float smin[8][B];        // 4 KB

    // Phase A0: stage H
    const int nfl = t * B;
    for (int i = tid * 4; i < nfl; i += 2048) {
        *(float4*)(&eH[0][0] + i) = *(const float4*)(H + i);
    }
    __syncthreads();

    const int b0 = lane, b1 = lane + 64;

    // Phase A2: stripe minima
    {
        const int rs = wv * 16;
        const int re = min(rs + 16, t);     // exclusive
        float sa = 1e30f, sb = 1e30f;
        for (int tau = rs; tau < re; ++tau) {
            sa = fminf(sa, eH[tau][b0]);
            sb = fminf(sb, eH[tau][b1]);
        }
        smin[wv][b0] = sa;
        smin[wv][b1] = sb;
    }
    __syncthreads();

    const float Ht1a = (t > 0) ? eH[t-1][b0] : 0.f;
    const float Ht1b = (t > 0) ? eH[t-1][b1] : 0.f;
    const float Hpa  = Ht1a + d1[t*B+b0] + d2[t*B+b0];   // H'_t
    const float Hpb  = Ht1b + d1[t*B+b1] + d2[t*B+b1];
    const float Aa   = u[t*B+b0] - Hpa;
    const float Ab   = u[t*B+b1] - Hpb;

    ushort* wrow0 = w + ((size_t)t * B + b0) * NS;
    ushort* wrow1 = w + ((size_t)t * B + b1) * NS;

    const int plo = wv * 16;
    if (plo <= t) {
        const int pe = min(plo + 15, t);
        float ma = 1e30f, mb = 1e30f;       // seed: min over stripes > wv
        #pragma unroll
        for (int s = 0; s < 8; ++s) {
            if (s > wv) { ma = fminf(ma, smin[s][b0]); mb = fminf(mb, smin[s][b1]); }
        }
        float s2a = 0.f, s3a = 0.f, s2b = 0.f, s3b = 0.f;
        float nd1a = d1[pe*B+b0], nd1b = d1[pe*B+b1];
        float nd2a = d2[pe*B+b0], nd2b = d2[pe*B+b1];
        for (int p = pe; p >= plo; --p) {
            const float d1a = nd1a, d1b = nd1b, d2a = nd2a, d2b = nd2b;
            if (p > plo) {
                nd1a = d1[(p-1)*B+b0]; nd1b = d1[(p-1)*B+b1];
                nd2a = d2[(p-1)*B+b0]; nd2b = d2[(p-1)*B+b1];
            }
            if (p < t) { ma = fminf(ma, eH[p][b0]); mb = fminf(mb, eH[p][b1]); }
            const float basea = (p > 0) ? eH[p-1][b0] : 0.f;
            const float baseb = (p > 0) ? eH[p-1][b1] : 0.f;
            const float top0a = basea + d1a, top0b = baseb + d1b;
            const float top1a = top0a + d2a, top1b = top0b + d2b;

            const float sa0 = fminf(fmaxf(ma - basea, 0.f), d1a);
            const float sb0 = fminf(fmaxf(mb - baseb, 0.f), d1b);
            const float sa1 = fminf(fmaxf(ma - top0a, 0.f), d2a);
            const float sb1 = fminf(fmaxf(mb - top0b, 0.f), d2b);

            float cand0 = fmaxf(Aa + fminf(top0a, ma), Ab + fminf(top0b, mb));
            float cand1 = fmaxf(Aa + fminf(top1a, ma), Ab + fminf(top1b, mb));
            #pragma unroll
            for (int off = 32; off >= 1; off >>= 1) {
                cand0 = fmaxf(cand0, __shfl_xor(cand0, off));
                cand1 = fmaxf(cand1, __shfl_xor(cand1, off));
            }

            const float w0a = fminf(sa0, cand0), w0b = fminf(sb0, cand0);
            const float w1a = fminf(sa1, cand1), w1b = fminf(sb1, cand1);
            if (p & 1) { s2a = w0a; s3a = w1a; s2b = w0b; s3b = w1b; }
            else {
                const int g = p >> 1;
                *(ushort4*)(wrow0 + 4*g) =
                    make_ushort4(f2bf(w0a), f2bf(w1a), f2bf(s2a), f2bf(s3a));
                *(ushort4*)(wrow1 + 4*g) =
                    make_ushort4(f2bf(w0b), f2bf(w1b), f2bf(s2b), f2bf(s3b));
            }
        }
    }

    // Phase C
    const int gstart = (t >> 1) + 1;
    const int ng = (NS / 4) - gstart;
    if (ng > 0) {
        const ushort4 z = make_ushort4(0, 0, 0, 0);
        const int total = ng * B;
        for (int idx = tid; idx < total; idx += 512) {
            const int gi = idx % ng;
            const int bb = idx / ng;
            *(ushort4*)(w + ((size_t)t*B + bb)*NS + 4*(gstart + gi)) = z;
        }
    }
}

// ---------------------------------------------------------------------------
// Kernel 2: bf16 MFMA GEMM — R6/R7 family, 3-LDS-buffer / 2-regset pipeline.
// Block = (b, r-tile 128), grid 512; 512 thr = 8 waves; wave wv owns
// t in [16wv,16wv+16) x 128 r. At iter c: issue loads for chunk c+2 (regset
// c&1), barrier, MFMA from buf c%3, then write chunk c+1 (regset (c+1)&1)
// to buf (c+1)%3 — load-to-wait distance = one full iteration.
// Zero-skip: MFMA only for chunk c <= wv; A-rows arow<16c stage zeros.
// ---------------------------------------------------------------------------
#define RT 128
__global__ __launch_bounds__(512) void gemm_mfma(
    const ushort* __restrict__ w, const float* __restrict__ v1,
    const float* __restrict__ v2, float* __restrict__ out)
{
    const int b    = blockIdx.x;
    const int r0   = blockIdx.y * RT;
    const int tid  = threadIdx.x;
    const int wv   = tid >> 6;          // 0..7
    const int lane = tid & 63;

    __shared__ ushort As[3][128][40];   // 30 KB
    __shared__ ushort Bs[3][128][40];   // 30 KB

    const int arow = tid >> 2;          // 0..127
    const int ajh  = (tid & 3) * 8;     // 0,8,16,24
    const ushort* abase = w + ((size_t)arow * B + b) * NS + ajh;

    const int p2   = tid & 15;
    const int rseg = tid >> 4;          // 0..31
    const float* v1b = v1 + (size_t)b * R + r0 + rseg * 4;
    const float* v2b = v2 + (size_t)b * R + r0 + rseg * 4;

    f32x4 acc[8];
    const f32x4 zz = {0.f, 0.f, 0.f, 0.f};
    #pragma unroll
    for (int i = 0; i < 8; ++i) acc[i] = zz;

    uint4 la[2];
    float4 lv1[2], lv2[2];

    #define STAGE_LOAD(s, c) do {                                       \
        if ((c) < 8) {                                                  \
            if (arow >= 16 * (c)) {                                     \
                la[s] = *(const uint4*)(abase + (c) * 32);              \
            } else {                                                    \
                la[s] = make_uint4(0u, 0u, 0u, 0u);                     \
            }                                                           \
            const size_t off_ = (size_t)((c) * 16 + p2) * B * R;        \
            lv1[s] = *(const float4*)(v1b + off_);                      \
            lv2[s] = *(const float4*)(v2b + off_);                      \
        }                                                               \
    } while (0)

    #define STAGE_WRITE(s, buf) do {                                    \
        *(uint4*)&As[buf][arow][ajh] = la[s];                           \
        const float* f1_ = (const float*)&lv1[s];                       \
        const float* f2_ = (const float*)&lv2[s];                       \
        _Pragma("unroll")                                               \
        for (int i_ = 0; i_ < 4; ++i_) {                                \
            unsigned pk_ = (unsigned)f2bf(f1_[i_]) |                    \
                           ((unsigned)f2bf(f2_[i_]) << 16);             \
            *(unsigned*)&Bs[buf][rseg * 4 + i_][p2 * 2] = pk_;          \
        }                                                               \
    } while (0)

    const int tb = wv * 16 + (lane & 15);
    const int ko = (lane >> 4) * 8;

    STAGE_LOAD(0, 0);
    STAGE_WRITE(0, 0);      // buf0 <- chunk 0
    STAGE_LOAD(1, 1);       // regset1 <- chunk 1

    #pragma unroll
    for (int c = 0; c < 8; ++c) {
        STAGE_LOAD(c & 1, c + 2);       // regset c&1 <- chunk c+2
        __syncthreads();
        if (c <= wv) {                  // chunks beyond this are all-zero A
            bf16x8 a0 = *(const bf16x8*)&As[c % 3][tb][ko];
            #pragma unroll
            for (int cf = 0; cf < 8; ++cf) {
                bf16x8 bb = *(const bf16x8*)&Bs[c % 3][cf*16 + (lane & 15)][ko];
                acc[cf] = __builtin_amdgcn_mfma_f32_16x16x32_bf16(a0, bb, acc[cf], 0, 0, 0);
            }
        }
        if (c < 7) STAGE_WRITE((c + 1) & 1, (c + 1) % 3);   // chunk c+1 -> LDS
    }

    const int dcol  = lane & 15;
    const int drow4 = (lane >> 4) * 4;
    #pragma unroll
    for (int cf = 0; cf < 8; ++cf) {
        const int rg = r0 + cf * 16 + dcol;
        #pragma unroll
        for (int i = 0; i < 4; ++i) {
            const int tg = wv * 16 + drow4 + i;
            out[((size_t)tg * B + b) * R + rg] = acc[cf][i];
        }
    }
    #undef STAGE_LOAD
    #undef STAGE_WRITE
}

extern "C" void kernel_launch(void* const* d_in, const int* in_sizes, int n_in,
                              void* d_out, int out_size, void* d_ws, size_t ws_size,
                              hipStream_t stream) {
    const float* u  = (const float*)d_in[0];
    const float* d1 = (const float*)d_in[1];
    const float* d2 = (const float*)d_in[2];
    const float* v1 = (const float*)d_in[3];
    const float* v2 = (const float*)d_in[4];
    float* out = (float*)d_out;

    const size_t welems = (size_t)T * B * NS;         // 4.19M ushorts
    ushort* w = (ushort*)d_ws;                        // 8.39 MB
    float* H;
    if (ws_size >= welems * sizeof(ushort) + (size_t)T * B * sizeof(float)) {
        H = (float*)((char*)d_ws + welems * sizeof(ushort));
    } else {
        H = (float*)d_out;   // 64 KB, dead before gemm overwrites it
    }

    hscan  <<<dim3(B / 2), dim3(128), 0, stream>>>(u, d1, d2, H);
    weights<<<dim3(T),     dim3(512), 0, stream>>>(u, d1, d2, H, w);
    gemm_mfma<<<dim3(B, R / RT), dim3(512), 0, stream>>>(w, v1, v2, out);
}

// Round 11
// 40.213 us; speedup vs baseline: 1.1581x; 1.0543x over previous
//
#include <hip/hip_runtime.h>
#include <hip/hip_bf16.h>
#include <math.h>

constexpr int T = 128;
constexpr int B = 128;
constexpr int R = 512;
constexpr int NS = 256;   // 2*T slots

typedef __attribute__((ext_vector_type(8))) short bf16x8;
typedef __attribute__((ext_vector_type(4))) float f32x4;

static __device__ __forceinline__ ushort f2bf(float f) {
    union { float f; unsigned u; } v; v.f = f;
    unsigned r = v.u + 0x7fffu + ((v.u >> 16) & 1u);   // RNE
    return (ushort)(r >> 16);
}

// ---------------------------------------------------------------------------
// Kernel 1: closed-form weights (R7 exact — best measured). Block = one t,
// 512 thr (8 waves). A0: stage e=d1+d2-u into LDS; A1: serial H chain
// (dep chain is add+fmax only, ~8 cyc/iter); A2: per-wave stripe minima;
// B: 16-iteration p-loop with shfl_xor cross-batch max; C: zero-fill tail.
// ---------------------------------------------------------------------------
__global__ __launch_bounds__(512) void weights(
    const float* __restrict__ u, const float* __restrict__ d1,
    const float* __restrict__ d2, ushort* __restrict__ w)
{
    const int t    = blockIdx.x;
    const int tid  = threadIdx.x;
    const int wv   = tid >> 6;          // 0..7
    const int lane = tid & 63;
    __shared__ float eH[T][B];          // 64 KB: e, overwritten with H
    __shared__ float smin[8][B];        // 4 KB stripe minima

    // Phase A0
    const int nfl = t * B;
    for (int i = tid * 4; i < nfl; i += 2048) {
        const float4 a  = *(const float4*)(d1 + i);
        const float4 b4 = *(const float4*)(d2 + i);
        const float4 c4 = *(const float4*)(u + i);
        *(float4*)(&eH[0][0] + i) =
            make_float4(a.x + b4.x - c4.x, a.y + b4.y - c4.y,
                        a.z + b4.z - c4.z, a.w + b4.w - c4.w);
    }
    __syncthreads();

    // Phase A1
    if (tid < B) {
        float h = 0.f;
        #pragma unroll 4
        for (int tt = 0; tt < t; ++tt) {
            h = fmaxf(0.f, h + eH[tt][tid]);
            eH[tt][tid] = h;
        }
    }
    __syncthreads();

    const int b0 = lane, b1 = lane + 64;

    // Phase A2: stripe minima
    {
        const int rs = wv * 16;
        const int re = min(rs + 16, t);     // exclusive
        float sa = 1e30f, sb = 1e30f;
        for (int tau = rs; tau < re; ++tau) {
            sa = fminf(sa, eH[tau][b0]);
            sb = fminf(sb, eH[tau][b1]);
        }
        smin[wv][b0] = sa;
        smin[wv][b1] = sb;
    }
    __syncthreads();

    const float Ht1a = (t > 0) ? eH[t-1][b0] : 0.f;
    const float Ht1b = (t > 0) ? eH[t-1][b1] : 0.f;
    const float Hpa  = Ht1a + d1[t*B+b0] + d2[t*B+b0];   // H'_t
    const float Hpb  = Ht1b + d1[t*B+b1] + d2[t*B+b1];
    const float Aa   = u[t*B+b0] - Hpa;
    const float Ab   = u[t*B+b1] - Hpb;

    ushort* wrow0 = w + ((size_t)t * B + b0) * NS;
    ushort* wrow1 = w + ((size_t)t * B + b1) * NS;

    const int plo = wv * 16;
    if (plo <= t) {
        const int pe = min(plo + 15, t);
        float ma = 1e30f, mb = 1e30f;       // seed: min over stripes > wv
        #pragma unroll
        for (int s = 0; s < 8; ++s) {
            if (s > wv) { ma = fminf(ma, smin[s][b0]); mb = fminf(mb, smin[s][b1]); }
        }
        float s2a = 0.f, s3a = 0.f, s2b = 0.f, s3b = 0.f;
        float nd1a = d1[pe*B+b0], nd1b = d1[pe*B+b1];
        float nd2a = d2[pe*B+b0], nd2b = d2[pe*B+b1];
        for (int p = pe; p >= plo; --p) {
            const float d1a = nd1a, d1b = nd1b, d2a = nd2a, d2b = nd2b;
            if (p > plo) {
                nd1a = d1[(p-1)*B+b0]; nd1b = d1[(p-1)*B+b1];
                nd2a = d2[(p-1)*B+b0]; nd2b = d2[(p-1)*B+b1];
            }
            if (p < t) { ma = fminf(ma, eH[p][b0]); mb = fminf(mb, eH[p][b1]); }
            const float basea = (p > 0) ? eH[p-1][b0] : 0.f;
            const float baseb = (p > 0) ? eH[p-1][b1] : 0.f;
            const float top0a = basea + d1a, top0b = baseb + d1b;
            const float top1a = top0a + d2a, top1b = top0b + d2b;

            const float sa0 = fminf(fmaxf(ma - basea, 0.f), d1a);
            const float sb0 = fminf(fmaxf(mb - baseb, 0.f), d1b);
            const float sa1 = fminf(fmaxf(ma - top0a, 0.f), d2a);
            const float sb1 = fminf(fmaxf(mb - top0b, 0.f), d2b);

            float cand0 = fmaxf(Aa + fminf(top0a, ma), Ab + fminf(top0b, mb));
            float cand1 = fmaxf(Aa + fminf(top1a, ma), Ab + fminf(top1b, mb));
            #pragma unroll
            for (int off = 32; off >= 1; off >>= 1) {
                cand0 = fmaxf(cand0, __shfl_xor(cand0, off));
                cand1 = fmaxf(cand1, __shfl_xor(cand1, off));
            }

            const float w0a = fminf(sa0, cand0), w0b = fminf(sb0, cand0);
            const float w1a = fminf(sa1, cand1), w1b = fminf(sb1, cand1);
            if (p & 1) { s2a = w0a; s3a = w1a; s2b = w0b; s3b = w1b; }
            else {
                const int g = p >> 1;
                *(ushort4*)(wrow0 + 4*g) =
                    make_ushort4(f2bf(w0a), f2bf(w1a), f2bf(s2a), f2bf(s3a));
                *(ushort4*)(wrow1 + 4*g) =
                    make_ushort4(f2bf(w0b), f2bf(w1b), f2bf(s2b), f2bf(s3b));
            }
        }
    }

    // Phase C
    const int gstart = (t >> 1) + 1;
    const int ng = (NS / 4) - gstart;
    if (ng > 0) {
        const ushort4 z = make_ushort4(0, 0, 0, 0);
        const int total = ng * B;
        for (int idx = tid; idx < total; idx += 512) {
            const int gi = idx % ng;
            const int bb = idx / ng;
            *(ushort4*)(w + ((size_t)t*B + bb)*NS + 4*(gstart + gi)) = z;
        }
    }
}

// ---------------------------------------------------------------------------
// Kernel 2: bf16 MFMA GEMM — R7 family, SINGLE CHANGE: A (w) loaded directly
// global->VGPR (no As LDS round-trip; 4 lanes/t-row = perfect 64B segments;
// w L2-resident per XCD since grid.x=b). A double-buffered in registers,
// issued one iteration ahead; zero-skip now skips A LOADS too (wave wv
// touches only chunks <= wv). Bs (V) staging unchanged (4x reuse in LDS).
// Block = (b, r-tile 128), grid 512; 512 thr = 8 waves.
// ---------------------------------------------------------------------------
#define RT 128
__global__ __launch_bounds__(512) void gemm_mfma(
    const ushort* __restrict__ w, const float* __restrict__ v1,
    const float* __restrict__ v2, float* __restrict__ out)
{
    const int b    = blockIdx.x;
    const int r0   = blockIdx.y * RT;
    const int tid  = threadIdx.x;
    const int wv   = tid >> 6;          // 0..7
    const int lane = tid & 63;

    __shared__ ushort Bs[2][128][40];   // [r][j] bf16, 20 KB

    // B staging: thread = (slot-pair p2 0..15, r-quad rseg 0..31)
    const int p2   = tid & 15;
    const int rseg = tid >> 4;          // 0..31
    const float* v1b = v1 + (size_t)b * R + r0 + rseg * 4;
    const float* v2b = v2 + (size_t)b * R + r0 + rseg * 4;

    // A direct: wave wv, lane row tb = wv*16 + (lane&15), k-off ko
    const int tb = wv * 16 + (lane & 15);
    const int ko = (lane >> 4) * 8;
    const ushort* warow = w + ((size_t)tb * B + b) * NS + ko;

    f32x4 acc[8];
    const f32x4 zz = {0.f, 0.f, 0.f, 0.f};
    #pragma unroll
    for (int i = 0; i < 8; ++i) acc[i] = zz;

    float4 lv1, lv2;
    bf16x8 a[2];

    #define STAGE_LOAD(c) do {                                          \
        const size_t off_ = (size_t)((c) * 16 + p2) * B * R;            \
        lv1 = *(const float4*)(v1b + off_);                             \
        lv2 = *(const float4*)(v2b + off_);                             \
    } while (0)

    #define STAGE_WRITE(buf) do {                                       \
        const float* f1_ = (const float*)&lv1;                          \
        const float* f2_ = (const float*)&lv2;                          \
        _Pragma("unroll")                                               \
        for (int i_ = 0; i_ < 4; ++i_) {                                \
            unsigned pk_ = (unsigned)f2bf(f1_[i_]) |                    \
                           ((unsigned)f2bf(f2_[i_]) << 16);             \
            *(unsigned*)&Bs[buf][rseg * 4 + i_][p2 * 2] = pk_;          \
        }                                                               \
    } while (0)

    #define ALOADR(s, c) do {                                           \
        if ((c) < 8 && (c) <= wv) {                                     \
            a[s] = *(const bf16x8*)(warow + (c) * 32);                  \
        }                                                               \
    } while (0)

    ALOADR(0, 0);
    STAGE_LOAD(0);
    STAGE_WRITE(0);          // Bs[0] <- chunk 0

    #pragma unroll
    for (int c = 0; c < 8; ++c) {
        const int buf = c & 1;
        if (c < 7) STAGE_LOAD(c + 1);
        ALOADR((c + 1) & 1, c + 1);
        __syncthreads();
        if (c <= wv) {                  // chunks beyond this are all-zero A
            #pragma unroll
            for (int cf = 0; cf < 8; ++cf) {
                bf16x8 bb = *(const bf16x8*)&Bs[buf][cf*16 + (lane & 15)][ko];
                acc[cf] = __builtin_amdgcn_mfma_f32_16x16x32_bf16(a[buf], bb, acc[cf], 0, 0, 0);
            }
        }
        if (c < 7) STAGE_WRITE((c + 1) & 1);
    }

    // epilogue: D col = lane&15 (r), row = (lane>>4)*4 + i (t)
    const int dcol  = lane & 15;
    const int drow4 = (lane >> 4) * 4;
    #pragma unroll
    for (int cf = 0; cf < 8; ++cf) {
        const int rg = r0 + cf * 16 + dcol;
        #pragma unroll
        for (int i = 0; i < 4; ++i) {
            const int tg = wv * 16 + drow4 + i;
            out[((size_t)tg * B + b) * R + rg] = acc[cf][i];
        }
    }
    #undef STAGE_LOAD
    #undef STAGE_WRITE
    #undef ALOADR
}

extern "C" void kernel_launch(void* const* d_in, const int* in_sizes, int n_in,
                              void* d_out, int out_size, void* d_ws, size_t ws_size,
                              hipStream_t stream) {
    const float* u  = (const float*)d_in[0];
    const float* d1 = (const float*)d_in[1];
    const float* d2 = (const float*)d_in[2];
    const float* v1 = (const float*)d_in[3];
    const float* v2 = (const float*)d_in[4];
    float* out = (float*)d_out;
    ushort* w  = (ushort*)d_ws;          // 8.39 MB bf16

    weights<<<dim3(T), dim3(512), 0, stream>>>(u, d1, d2, w);
    // grid.x = b (fastest): all r-tiles of a given b land on XCD b%8 -> w L2 reuse
    gemm_mfma<<<dim3(B, R / RT), dim3(512), 0, stream>>>(w, v1, v2, out);
}